// Round 1
// baseline (654.032 us; speedup 1.0000x reference)
//
#include <hip/hip_runtime.h>
#include <hip/hip_bf16.h>

#define E_ 8
#define H_ 2048
#define I_ 1024
#define T_ 16384
#define BM 128
#define BN 128
#define BK 32
#define MAX_MT 136   // max m-tiles: T/128 + E partial tiles

typedef __bf16 bf16x8 __attribute__((ext_vector_type(8)));
typedef float f32x4 __attribute__((ext_vector_type(4)));

__device__ __forceinline__ unsigned short f2bf(float f) {
  unsigned int x = __float_as_uint(f);
  x += 0x7FFFu + ((x >> 16) & 1u);   // round-to-nearest-even
  return (unsigned short)(x >> 16);
}

__device__ __forceinline__ void gl_lds16(const void* g, void* s) {
  __builtin_amdgcn_global_load_lds(
      (const __attribute__((address_space(1))) void*)g,
      (__attribute__((address_space(3))) void*)s, 16, 0, 0);
}

// Map linear m-tile index -> (expert, row0, rowEnd). Returns false for idle blocks.
__device__ __forceinline__ bool find_tile(const int* gs, int tile, int& e,
                                          int& row0, int& rowEnd) {
  int base = 0, tb = 0;
  e = -1;
  for (int i = 0; i < E_; i++) {
    int g = gs[i];
    int nt = (g + BM - 1) >> 7;
    if (e < 0 && tile < tb + nt) {
      e = i;
      row0 = base + (tile - tb) * BM;
      rowEnd = base + g;
    }
    tb += nt;
    base += g;
  }
  return e >= 0;
}

// ---------------- conversion kernels ----------------

// fp32 [T,H] -> bf16 [T,H], 8 elems/thread
__global__ void cvt_hs(const float* __restrict__ in, ushort* __restrict__ out) {
  size_t i = ((size_t)blockIdx.x * 256 + threadIdx.x) * 8;
  float4 a = *(const float4*)(in + i);
  float4 b = *(const float4*)(in + i + 4);
  union { ushort u[8]; uint4 v; } p;
  p.u[0] = f2bf(a.x); p.u[1] = f2bf(a.y); p.u[2] = f2bf(a.z); p.u[3] = f2bf(a.w);
  p.u[4] = f2bf(b.x); p.u[5] = f2bf(b.y); p.u[6] = f2bf(b.z); p.u[7] = f2bf(b.w);
  *(uint4*)(out + i) = p.v;
}

// fp32 [e][K][N] -> bf16 [e][N][K] (transpose-convert), 64x64 tiles
__global__ void cvt_tr(const float* __restrict__ in, ushort* __restrict__ out,
                       int K, int N) {
  __shared__ ushort tile[64][65];   // +1 pad: 2-way max on both phases (free)
  int n0 = blockIdx.x * 64, k0 = blockIdx.y * 64;
  const float* src = in + (size_t)blockIdx.z * K * N;
  ushort* dst = out + (size_t)blockIdx.z * K * N;
  int t = threadIdx.x;
  int rb = t >> 4, c4 = (t & 15) * 4;
#pragma unroll
  for (int i = 0; i < 4; i++) {
    int r = rb + i * 16;
    float4 v = *(const float4*)(src + (size_t)(k0 + r) * N + n0 + c4);
    tile[r][c4 + 0] = f2bf(v.x);
    tile[r][c4 + 1] = f2bf(v.y);
    tile[r][c4 + 2] = f2bf(v.z);
    tile[r][c4 + 3] = f2bf(v.w);
  }
  __syncthreads();
#pragma unroll
  for (int i = 0; i < 2; i++) {
    int c = t + i * 256;
    int n = c >> 3, kc = c & 7;
    union { ushort u[8]; uint4 v; } p;
#pragma unroll
    for (int j = 0; j < 8; j++) p.u[j] = tile[kc * 8 + j][n];
    *(uint4*)(dst + (size_t)(n0 + n) * K + k0 + kc * 8) = p.v;
  }
}

// ---------------- fused gate/up GEMM + SwiGLU ----------------
// A [T,H] bf16 ; BgT,BuT [E][I][H] bf16 (n-major, k-contiguous) ; Hb [T,I] bf16
__global__ __launch_bounds__(256, 2) void gemm_gateup(
    const ushort* __restrict__ A, const ushort* __restrict__ BgT,
    const ushort* __restrict__ BuT, const int* __restrict__ gs,
    ushort* __restrict__ Hb) {
  __shared__ __align__(16) ushort sA[BM * BK];
  __shared__ __align__(16) ushort sG[BN * BK];
  __shared__ __align__(16) ushort sU[BN * BK];

  int e, row0, rowEnd;
  if (!find_tile(gs, blockIdx.x, e, row0, rowEnd)) return;
  const int n0 = blockIdx.y * BN;

  const int t = threadIdx.x;
  const int lane = t & 63;
  const int w = t >> 6;
  const int wm = w & 1, wn = w >> 1;

  // staging: 512 chunks of 16B per tile; chunk c -> row c>>2, k-chunk c&3
  const int c0 = t, c1 = t + 256;
  const int r0 = c0 >> 2, kc0 = c0 & 3;
  const int r1 = c1 >> 2, kc1 = c1 & 3;
  int ar0 = row0 + r0; if (ar0 > T_ - 1) ar0 = T_ - 1;
  int ar1 = row0 + r1; if (ar1 > T_ - 1) ar1 = T_ - 1;

  const ushort* pa0 = A + (size_t)ar0 * H_ + kc0 * 8;
  const ushort* pa1 = A + (size_t)ar1 * H_ + kc1 * 8;
  const ushort* bgb = BgT + ((size_t)e * I_ + n0) * H_;
  const ushort* bub = BuT + ((size_t)e * I_ + n0) * H_;
  const ushort* pg0 = bgb + (size_t)r0 * H_ + kc0 * 8;
  const ushort* pg1 = bgb + (size_t)r1 * H_ + kc1 * 8;
  const ushort* pu0 = bub + (size_t)r0 * H_ + kc0 * 8;
  const ushort* pu1 = bub + (size_t)r1 * H_ + kc1 * 8;

  ushort* dA0 = &sA[w * 512]; ushort* dA1 = &sA[2048 + w * 512];
  ushort* dG0 = &sG[w * 512]; ushort* dG1 = &sG[2048 + w * 512];
  ushort* dU0 = &sU[w * 512]; ushort* dU1 = &sU[2048 + w * 512];

  const int koff = (lane >> 4) * 8;
  const ushort* aF = &sA[(wm * 64 + (lane & 15)) * BK + koff];
  const ushort* gF = &sG[(wn * 64 + (lane & 15)) * BK + koff];
  const ushort* uF = &sU[(wn * 64 + (lane & 15)) * BK + koff];

  f32x4 accG[4][4], accU[4][4];
#pragma unroll
  for (int mi = 0; mi < 4; mi++)
#pragma unroll
    for (int ni = 0; ni < 4; ni++) {
      accG[mi][ni] = (f32x4){0.f, 0.f, 0.f, 0.f};
      accU[mi][ni] = (f32x4){0.f, 0.f, 0.f, 0.f};
    }

  for (int k0 = 0; k0 < H_; k0 += BK) {
    gl_lds16(pa0, dA0); gl_lds16(pa1, dA1);
    gl_lds16(pg0, dG0); gl_lds16(pg1, dG1);
    gl_lds16(pu0, dU0); gl_lds16(pu1, dU1);
    pa0 += BK; pa1 += BK; pg0 += BK; pg1 += BK; pu0 += BK; pu1 += BK;
    __syncthreads();   // drains global_load_lds (vmcnt 0) + barrier

    bf16x8 af[4], gf[4], uf[4];
#pragma unroll
    for (int i = 0; i < 4; i++) {
      af[i] = *(const bf16x8*)(aF + i * 16 * BK);
      gf[i] = *(const bf16x8*)(gF + i * 16 * BK);
      uf[i] = *(const bf16x8*)(uF + i * 16 * BK);
    }
#pragma unroll
    for (int mi = 0; mi < 4; mi++)
#pragma unroll
      for (int ni = 0; ni < 4; ni++) {
        accG[mi][ni] = __builtin_amdgcn_mfma_f32_16x16x32_bf16(af[mi], gf[ni], accG[mi][ni], 0, 0, 0);
        accU[mi][ni] = __builtin_amdgcn_mfma_f32_16x16x32_bf16(af[mi], uf[ni], accU[mi][ni], 0, 0, 0);
      }
    __syncthreads();
  }

  // epilogue: h = silu(g)*u, bf16 store. C/D layout: col=lane&15, row=(lane>>4)*4+r
  const int crow = row0 + wm * 64 + ((lane >> 4) << 2);
  const int ccol = n0 + wn * 64 + (lane & 15);
#pragma unroll
  for (int mi = 0; mi < 4; mi++)
#pragma unroll
    for (int ni = 0; ni < 4; ni++)
#pragma unroll
      for (int r = 0; r < 4; r++) {
        int row = crow + mi * 16 + r;
        if (row < rowEnd) {
          float g = accG[mi][ni][r];
          float u = accU[mi][ni][r];
          float h = (g / (1.0f + __expf(-g))) * u;
          Hb[(size_t)row * I_ + ccol + ni * 16] = f2bf(h);
        }
      }
}

// ---------------- down GEMM ----------------
// A=Hb [T,I] bf16 ; BdT [E][H][I] bf16 ; out [T,H] fp32
__global__ __launch_bounds__(256, 2) void gemm_down(
    const ushort* __restrict__ A, const ushort* __restrict__ BdT,
    const int* __restrict__ gs, float* __restrict__ Out) {
  __shared__ __align__(16) ushort sA[BM * BK];
  __shared__ __align__(16) ushort sB[BN * BK];

  int e, row0, rowEnd;
  if (!find_tile(gs, blockIdx.x, e, row0, rowEnd)) return;
  const int n0 = blockIdx.y * BN;

  const int t = threadIdx.x;
  const int lane = t & 63;
  const int w = t >> 6;
  const int wm = w & 1, wn = w >> 1;

  const int c0 = t, c1 = t + 256;
  const int r0 = c0 >> 2, kc0 = c0 & 3;
  const int r1 = c1 >> 2, kc1 = c1 & 3;
  int ar0 = row0 + r0; if (ar0 > T_ - 1) ar0 = T_ - 1;
  int ar1 = row0 + r1; if (ar1 > T_ - 1) ar1 = T_ - 1;

  const ushort* pa0 = A + (size_t)ar0 * I_ + kc0 * 8;
  const ushort* pa1 = A + (size_t)ar1 * I_ + kc1 * 8;
  const ushort* bb = BdT + ((size_t)e * H_ + n0) * I_;
  const ushort* pb0 = bb + (size_t)r0 * I_ + kc0 * 8;
  const ushort* pb1 = bb + (size_t)r1 * I_ + kc1 * 8;

  ushort* dA0 = &sA[w * 512]; ushort* dA1 = &sA[2048 + w * 512];
  ushort* dB0 = &sB[w * 512]; ushort* dB1 = &sB[2048 + w * 512];

  const int koff = (lane >> 4) * 8;
  const ushort* aF = &sA[(wm * 64 + (lane & 15)) * BK + koff];
  const ushort* bF = &sB[(wn * 64 + (lane & 15)) * BK + koff];

  f32x4 acc[4][4];
#pragma unroll
  for (int mi = 0; mi < 4; mi++)
#pragma unroll
    for (int ni = 0; ni < 4; ni++) acc[mi][ni] = (f32x4){0.f, 0.f, 0.f, 0.f};

  for (int k0 = 0; k0 < I_; k0 += BK) {
    gl_lds16(pa0, dA0); gl_lds16(pa1, dA1);
    gl_lds16(pb0, dB0); gl_lds16(pb1, dB1);
    pa0 += BK; pa1 += BK; pb0 += BK; pb1 += BK;
    __syncthreads();

    bf16x8 af[4], bf[4];
#pragma unroll
    for (int i = 0; i < 4; i++) {
      af[i] = *(const bf16x8*)(aF + i * 16 * BK);
      bf[i] = *(const bf16x8*)(bF + i * 16 * BK);
    }
#pragma unroll
    for (int mi = 0; mi < 4; mi++)
#pragma unroll
      for (int ni = 0; ni < 4; ni++)
        acc[mi][ni] = __builtin_amdgcn_mfma_f32_16x16x32_bf16(af[mi], bf[ni], acc[mi][ni], 0, 0, 0);
    __syncthreads();
  }

  const int crow = row0 + wm * 64 + ((lane >> 4) << 2);
  const int ccol = n0 + wn * 64 + (lane & 15);
#pragma unroll
  for (int mi = 0; mi < 4; mi++)
#pragma unroll
    for (int ni = 0; ni < 4; ni++)
#pragma unroll
      for (int r = 0; r < 4; r++) {
        int row = crow + mi * 16 + r;
        if (row < rowEnd) Out[(size_t)row * H_ + ccol + ni * 16] = acc[mi][ni][r];
      }
}

extern "C" void kernel_launch(void* const* d_in, const int* in_sizes, int n_in,
                              void* d_out, int out_size, void* d_ws, size_t ws_size,
                              hipStream_t stream) {
  const float* hs = (const float*)d_in[0];
  const float* gw = (const float*)d_in[1];
  const float* uw = (const float*)d_in[2];
  const float* dw = (const float*)d_in[3];
  const int* gs = (const int*)d_in[4];
  float* out = (float*)d_out;

  // workspace layout (bf16/ushort elements), total ~192 MiB
  ushort* hsb = (ushort*)d_ws;                       // [T,H]
  ushort* wgT = hsb + (size_t)T_ * H_;               // [E,I,H]
  ushort* wuT = wgT + (size_t)E_ * H_ * I_;          // [E,I,H]
  ushort* wdT = wuT + (size_t)E_ * H_ * I_;          // [E,H,I]
  ushort* hb  = wdT + (size_t)E_ * H_ * I_;          // [T,I]

  cvt_hs<<<((size_t)T_ * H_) / (256 * 8), 256, 0, stream>>>(hs, hsb);
  cvt_tr<<<dim3(I_ / 64, H_ / 64, E_), 256, 0, stream>>>(gw, wgT, H_, I_);
  cvt_tr<<<dim3(I_ / 64, H_ / 64, E_), 256, 0, stream>>>(uw, wuT, H_, I_);
  cvt_tr<<<dim3(H_ / 64, I_ / 64, E_), 256, 0, stream>>>(dw, wdT, I_, H_);

  gemm_gateup<<<dim3(MAX_MT, I_ / BN), 256, 0, stream>>>(hsb, wgT, wuT, gs, hb);
  gemm_down<<<dim3(MAX_MT, H_ / BN), 256, 0, stream>>>(hb, wdT, gs, out);
}

// Round 3
// 600.436 us; speedup vs baseline: 1.0893x; 1.0893x over previous
//
#include <hip/hip_runtime.h>
#include <hip/hip_bf16.h>

#define E_ 8
#define H_ 2048
#define I_ 1024
#define T_ 16384
#define BM 128
#define BN 128
#define BK 64
#define MAX_MT 136   // max m-tiles: T/128 + E partial tiles

typedef __bf16 bf16x8 __attribute__((ext_vector_type(8)));
typedef float f32x4 __attribute__((ext_vector_type(4)));

__device__ __forceinline__ unsigned short f2bf(float f) {
  unsigned int x = __float_as_uint(f);
  x += 0x7FFFu + ((x >> 16) & 1u);   // round-to-nearest-even
  return (unsigned short)(x >> 16);
}

__device__ __forceinline__ void gl_lds16(const void* g, void* s) {
  __builtin_amdgcn_global_load_lds(
      (const __attribute__((address_space(1))) void*)g,
      (__attribute__((address_space(3))) void*)s, 16, 0, 0);
}

// Full drain (vmcnt=0, expcnt=0, lgkmcnt=0) + barrier. The explicit waitcnt
// guards against the waitcnt-insertion pass under-draining outstanding
// global_load_lds DMAs at the barrier (suspected round-2 replay race).
__device__ __forceinline__ void sync_full() {
  __builtin_amdgcn_s_waitcnt(0);
  __syncthreads();
}

// Map linear m-tile index -> (expert, row0, rowEnd). Returns false for idle blocks.
__device__ __forceinline__ bool find_tile(const int* gs, int tile, int& e,
                                          int& row0, int& rowEnd) {
  int base = 0, tb = 0;
  e = -1;
  for (int i = 0; i < E_; i++) {
    int g = gs[i];
    int nt = (g + BM - 1) >> 7;
    if (e < 0 && tile < tb + nt) {
      e = i;
      row0 = base + (tile - tb) * BM;
      rowEnd = base + g;
    }
    tb += nt;
    base += g;
  }
  return e >= 0;
}

// ---------------- conversion kernels ----------------

// fp32 [T,H] -> bf16 [T,H], 8 elems/thread
__global__ void cvt_hs(const float* __restrict__ in, ushort* __restrict__ out) {
  size_t i = ((size_t)blockIdx.x * 256 + threadIdx.x) * 8;
  float4 a = *(const float4*)(in + i);
  float4 b = *(const float4*)(in + i + 4);
  union { ushort u[8]; uint4 v; } p;
  p.u[0] = f2bf(a.x); p.u[1] = f2bf(a.y); p.u[2] = f2bf(a.z); p.u[3] = f2bf(a.w);
  p.u[4] = f2bf(b.x); p.u[5] = f2bf(b.y); p.u[6] = f2bf(b.z); p.u[7] = f2bf(b.w);
  *(uint4*)(out + i) = p.v;
}

// fp32 [e][K][N] -> bf16 [e][N][K] (transpose-convert), 64x64 tiles
__global__ void cvt_tr(const float* __restrict__ in, ushort* __restrict__ out,
                       int K, int N) {
  __shared__ ushort tile[64][65];
  int n0 = blockIdx.x * 64, k0 = blockIdx.y * 64;
  const float* src = in + (size_t)blockIdx.z * K * N;
  ushort* dst = out + (size_t)blockIdx.z * K * N;
  int t = threadIdx.x;
  int rb = t >> 4, c4 = (t & 15) * 4;
#pragma unroll
  for (int i = 0; i < 4; i++) {
    int r = rb + i * 16;
    float4 v = *(const float4*)(src + (size_t)(k0 + r) * N + n0 + c4);
    tile[r][c4 + 0] = f2bf(v.x);
    tile[r][c4 + 1] = f2bf(v.y);
    tile[r][c4 + 2] = f2bf(v.z);
    tile[r][c4 + 3] = f2bf(v.w);
  }
  __syncthreads();
#pragma unroll
  for (int i = 0; i < 2; i++) {
    int c = t + i * 256;
    int n = c >> 3, kc = c & 7;
    union { ushort u[8]; uint4 v; } p;
#pragma unroll
    for (int j = 0; j < 8; j++) p.u[j] = tile[kc * 8 + j][n];
    *(uint4*)(dst + (size_t)(n0 + n) * K + k0 + kc * 8) = p.v;
  }
}

// ---------------- fused gate/up GEMM + SwiGLU ----------------
// LDS layout (per tile, 128 rows x 64 ushorts): 16B chunk index c holds
// global (r = c>>3, kc = (c&7) ^ (r&7)) -- XOR swizzle kills the 8-way bank
// conflict on b128 fragment reads while keeping the global_load_lds
// wave-uniform-base + lane*16 contiguity requirement.
__global__ __launch_bounds__(256, 2) void gemm_gateup(
    const ushort* __restrict__ A, const ushort* __restrict__ BgT,
    const ushort* __restrict__ BuT, const int* __restrict__ gs,
    ushort* __restrict__ Hb) {
  __shared__ __align__(16) ushort sA[BM * BK];
  __shared__ __align__(16) ushort sG[BN * BK];
  __shared__ __align__(16) ushort sU[BN * BK];

  int e, row0, rowEnd;
  if (!find_tile(gs, blockIdx.x, e, row0, rowEnd)) return;
  const int n0 = blockIdx.y * BN;

  const int t = threadIdx.x;
  const int lane = t & 63;
  const int w = t >> 6;
  const int wm = w & 1, wn = w >> 1;

  // staging: 1024 chunks of 16B per tile; thread t stages chunks c = i*256+t
  int offAB[4];  // element offset within a [128 x H_] row-block (swizzled)
  int offA[4];   // absolute element offset into A (row-clamped)
#pragma unroll
  for (int i = 0; i < 4; i++) {
    int c = i * 256 + t;
    int r = c >> 3;
    int kcs = (c & 7) ^ (r & 7);
    offAB[i] = r * H_ + kcs * 8;
    int ar = row0 + r; if (ar > T_ - 1) ar = T_ - 1;
    offA[i] = ar * H_ + kcs * 8;
  }
  const ushort* pA = A;
  const ushort* pG = BgT + ((size_t)e * I_ + n0) * H_;
  const ushort* pU = BuT + ((size_t)e * I_ + n0) * H_;
  const int ldst = w * 64 * 8;   // ushort idx: wave w's 64-chunk slice

  // fragment read pointers (kstep 0/1); swizzled
  const int l15 = lane & 15, l7 = lane & 7, lk = lane >> 4;
  const int sw0 = (lk ^ l7) * 8;
  const int sw1 = ((lk + 4) ^ l7) * 8;
  const ushort* aF0 = sA + (wm * 64 + l15) * BK + sw0;
  const ushort* aF1 = sA + (wm * 64 + l15) * BK + sw1;
  const ushort* gF0 = sG + (wn * 64 + l15) * BK + sw0;
  const ushort* gF1 = sG + (wn * 64 + l15) * BK + sw1;
  const ushort* uF0 = sU + (wn * 64 + l15) * BK + sw0;
  const ushort* uF1 = sU + (wn * 64 + l15) * BK + sw1;

  f32x4 accG[4][4], accU[4][4];
#pragma unroll
  for (int mi = 0; mi < 4; mi++)
#pragma unroll
    for (int ni = 0; ni < 4; ni++) {
      accG[mi][ni] = (f32x4){0.f, 0.f, 0.f, 0.f};
      accU[mi][ni] = (f32x4){0.f, 0.f, 0.f, 0.f};
    }

  for (int k0 = 0; k0 < H_; k0 += BK) {
#pragma unroll
    for (int i = 0; i < 4; i++) {
      gl_lds16(pA + offA[i],  sA + i * 2048 + ldst);
      gl_lds16(pG + offAB[i], sG + i * 2048 + ldst);
      gl_lds16(pU + offAB[i], sU + i * 2048 + ldst);
    }
    pA += BK; pG += BK; pU += BK;
    sync_full();   // explicit vmcnt(0) drain + barrier

#pragma unroll
    for (int ks = 0; ks < 2; ks++) {
      bf16x8 af[4], gf[4], uf[4];
#pragma unroll
      for (int i = 0; i < 4; i++) {
        af[i] = *(const bf16x8*)((ks ? aF1 : aF0) + i * 16 * BK);
        gf[i] = *(const bf16x8*)((ks ? gF1 : gF0) + i * 16 * BK);
        uf[i] = *(const bf16x8*)((ks ? uF1 : uF0) + i * 16 * BK);
      }
#pragma unroll
      for (int mi = 0; mi < 4; mi++)
#pragma unroll
        for (int ni = 0; ni < 4; ni++) {
          accG[mi][ni] = __builtin_amdgcn_mfma_f32_16x16x32_bf16(af[mi], gf[ni], accG[mi][ni], 0, 0, 0);
          accU[mi][ni] = __builtin_amdgcn_mfma_f32_16x16x32_bf16(af[mi], uf[ni], accU[mi][ni], 0, 0, 0);
        }
    }
    sync_full();   // all lds reads done in all waves before next staging
  }

  // epilogue: h = silu(g)*u, bf16 store. C/D: col=lane&15, row=(lane>>4)*4+r
  const int crow = row0 + wm * 64 + ((lane >> 4) << 2);
  const int ccol = n0 + wn * 64 + (lane & 15);
#pragma unroll
  for (int mi = 0; mi < 4; mi++)
#pragma unroll
    for (int ni = 0; ni < 4; ni++)
#pragma unroll
      for (int r = 0; r < 4; r++) {
        int row = crow + mi * 16 + r;
        if (row < rowEnd) {
          float g = accG[mi][ni][r];
          float u = accU[mi][ni][r];
          float h = (g / (1.0f + __expf(-g))) * u;
          Hb[(size_t)row * I_ + ccol + ni * 16] = f2bf(h);
        }
      }
}

// ---------------- down GEMM ----------------
// A=Hb [T,I] bf16 ; BdT [E][H][I] bf16 ; out [T,H] fp32. Same swizzled BK=64.
__global__ __launch_bounds__(256, 3) void gemm_down(
    const ushort* __restrict__ A, const ushort* __restrict__ BdT,
    const int* __restrict__ gs, float* __restrict__ Out) {
  __shared__ __align__(16) ushort sA[BM * BK];
  __shared__ __align__(16) ushort sB[BN * BK];

  int e, row0, rowEnd;
  if (!find_tile(gs, blockIdx.x, e, row0, rowEnd)) return;
  const int n0 = blockIdx.y * BN;

  const int t = threadIdx.x;
  const int lane = t & 63;
  const int w = t >> 6;
  const int wm = w & 1, wn = w >> 1;

  int offB[4], offA[4];
#pragma unroll
  for (int i = 0; i < 4; i++) {
    int c = i * 256 + t;
    int r = c >> 3;
    int kcs = (c & 7) ^ (r & 7);
    offB[i] = r * I_ + kcs * 8;
    int ar = row0 + r; if (ar > T_ - 1) ar = T_ - 1;
    offA[i] = ar * I_ + kcs * 8;
  }
  const ushort* pA = A;
  const ushort* pB = BdT + ((size_t)e * H_ + n0) * I_;
  const int ldst = w * 64 * 8;

  const int l15 = lane & 15, l7 = lane & 7, lk = lane >> 4;
  const int sw0 = (lk ^ l7) * 8;
  const int sw1 = ((lk + 4) ^ l7) * 8;
  const ushort* aF0 = sA + (wm * 64 + l15) * BK + sw0;
  const ushort* aF1 = sA + (wm * 64 + l15) * BK + sw1;
  const ushort* bF0 = sB + (wn * 64 + l15) * BK + sw0;
  const ushort* bF1 = sB + (wn * 64 + l15) * BK + sw1;

  f32x4 acc[4][4];
#pragma unroll
  for (int mi = 0; mi < 4; mi++)
#pragma unroll
    for (int ni = 0; ni < 4; ni++) acc[mi][ni] = (f32x4){0.f, 0.f, 0.f, 0.f};

  for (int k0 = 0; k0 < I_; k0 += BK) {
#pragma unroll
    for (int i = 0; i < 4; i++) {
      gl_lds16(pA + offA[i], sA + i * 2048 + ldst);
      gl_lds16(pB + offB[i], sB + i * 2048 + ldst);
    }
    pA += BK; pB += BK;
    sync_full();

#pragma unroll
    for (int ks = 0; ks < 2; ks++) {
      bf16x8 af[4], bf[4];
#pragma unroll
      for (int i = 0; i < 4; i++) {
        af[i] = *(const bf16x8*)((ks ? aF1 : aF0) + i * 16 * BK);
        bf[i] = *(const bf16x8*)((ks ? bF1 : bF0) + i * 16 * BK);
      }
#pragma unroll
      for (int mi = 0; mi < 4; mi++)
#pragma unroll
        for (int ni = 0; ni < 4; ni++)
          acc[mi][ni] = __builtin_amdgcn_mfma_f32_16x16x32_bf16(af[mi], bf[ni], acc[mi][ni], 0, 0, 0);
    }
    sync_full();
  }

  const int crow = row0 + wm * 64 + ((lane >> 4) << 2);
  const int ccol = n0 + wn * 64 + (lane & 15);
#pragma unroll
  for (int mi = 0; mi < 4; mi++)
#pragma unroll
    for (int ni = 0; ni < 4; ni++)
#pragma unroll
      for (int r = 0; r < 4; r++) {
        int row = crow + mi * 16 + r;
        if (row < rowEnd) Out[(size_t)row * H_ + ccol + ni * 16] = acc[mi][ni][r];
      }
}

extern "C" void kernel_launch(void* const* d_in, const int* in_sizes, int n_in,
                              void* d_out, int out_size, void* d_ws, size_t ws_size,
                              hipStream_t stream) {
  const float* hs = (const float*)d_in[0];
  const float* gw = (const float*)d_in[1];
  const float* uw = (const float*)d_in[2];
  const float* dw = (const float*)d_in[3];
  const int* gs = (const int*)d_in[4];
  float* out = (float*)d_out;

  ushort* hsb = (ushort*)d_ws;                       // [T,H]
  ushort* wgT = hsb + (size_t)T_ * H_;               // [E,I,H]
  ushort* wuT = wgT + (size_t)E_ * H_ * I_;          // [E,I,H]
  ushort* wdT = wuT + (size_t)E_ * H_ * I_;          // [E,H,I]
  ushort* hb  = wdT + (size_t)E_ * H_ * I_;          // [T,I]

  cvt_hs<<<((size_t)T_ * H_) / (256 * 8), 256, 0, stream>>>(hs, hsb);
  cvt_tr<<<dim3(I_ / 64, H_ / 64, E_), 256, 0, stream>>>(gw, wgT, H_, I_);
  cvt_tr<<<dim3(I_ / 64, H_ / 64, E_), 256, 0, stream>>>(uw, wuT, H_, I_);
  cvt_tr<<<dim3(H_ / 64, I_ / 64, E_), 256, 0, stream>>>(dw, wdT, I_, H_);

  gemm_gateup<<<dim3(MAX_MT, I_ / BN), 256, 0, stream>>>(hsb, wgT, wuT, gs, hb);
  gemm_down<<<dim3(MAX_MT, H_ / BN), 256, 0, stream>>>(hb, wdT, gs, out);
}